// Round 1
// baseline (6185.045 us; speedup 1.0000x reference)
//
#include <hip/hip_runtime.h>

// GCN 2-layer forward, N=50000 nodes, F=128 features, E=1.6M edges (+self loops).
//
// Math restructuring:
//   h'   = (x @ W^T + b) * dinv[row]          (dinv = deg^-1/2, deg incl. self loop)
//   acc  = h'  (self-loop)  then  acc[dst] += h'[src]  over edges
//   out  = acc * dinv[row]   (+ relu between layers)
//
// ws layout: [0, 200KB)   dinv (50000 f32)
//            [1MB, 26.6MB)  h buffer (50000x128 f32)
//            [26.6MB, 52.3MB) acc buffer for layer 1
// d_out doubles as the layer-2 accumulator.

static constexpr int F = 128;

__global__ void k_deg_init(float* __restrict__ deg, int n) {
  int i = blockIdx.x * blockDim.x + threadIdx.x;
  if (i < n) deg[i] = 1.0f;  // self loop
}

__global__ void k_deg_count(const int* __restrict__ dst, int E,
                            float* __restrict__ deg) {
  int i = blockIdx.x * blockDim.x + threadIdx.x;
  if (i < E) atomicAdd(&deg[dst[i]], 1.0f);
}

__global__ void k_dinv(float* __restrict__ deg, int n) {
  int i = blockIdx.x * blockDim.x + threadIdx.x;
  if (i < n) deg[i] = rsqrtf(deg[i]);  // deg >= 1 always (self loops)
}

// hout[row,:] = acc[row,:] = (in[row,:] @ W^T + bias) * dinv[row]
__global__ __launch_bounds__(256) void k_linear_scale(
    const float* __restrict__ in, const float* __restrict__ W,
    const float* __restrict__ bias, const float* __restrict__ dinv,
    float* __restrict__ hout, float* __restrict__ acc, int n) {
  const int half = threadIdx.x >> 7;  // 2 rows per block
  const int j = threadIdx.x & (F - 1);
  const int row = blockIdx.x * 2 + half;
  __shared__ float xs[2][F];
  if (row < n) xs[half][j] = in[row * F + j];
  __syncthreads();
  if (row >= n) return;
  const float4* __restrict__ Wr = (const float4*)(W + j * F);
  const float4* __restrict__ xr = (const float4*)(xs[half]);
  float s = 0.f;
#pragma unroll
  for (int k = 0; k < F / 4; ++k) {
    const float4 w = Wr[k];
    const float4 xv = xr[k];
    s += w.x * xv.x + w.y * xv.y + w.z * xv.z + w.w * xv.w;
  }
  s = (s + bias[j]) * dinv[row];
  hout[row * F + j] = s;
  acc[row * F + j] = s;  // self-loop init
}

// acc[dst[e],:] += h[src[e],:]   (32 threads/edge, float4 each)
__global__ __launch_bounds__(256) void k_scatter(
    const int* __restrict__ src, const int* __restrict__ dst, int E,
    const float* __restrict__ h, float* __restrict__ acc) {
  int t = blockIdx.x * blockDim.x + threadIdx.x;
  int e = t >> 5;
  if (e >= E) return;
  int lane = t & 31;
  int s = src[e];
  int d = dst[e];
  const float4 v = *(const float4*)(h + s * F + lane * 4);
  float* a = acc + d * F + lane * 4;
  atomicAdd(a + 0, v.x);
  atomicAdd(a + 1, v.y);
  atomicAdd(a + 2, v.z);
  atomicAdd(a + 3, v.w);
}

// in-place: v = relu(v * dinv[row])
__global__ void k_relu_scale(float4* __restrict__ acc,
                             const float* __restrict__ dinv, int n4) {
  int i = blockIdx.x * blockDim.x + threadIdx.x;
  if (i >= n4) return;
  const float dv = dinv[i >> 5];  // 32 float4 per row
  float4 v = acc[i];
  v.x = fmaxf(v.x * dv, 0.f);
  v.y = fmaxf(v.y * dv, 0.f);
  v.z = fmaxf(v.z * dv, 0.f);
  v.w = fmaxf(v.w * dv, 0.f);
  acc[i] = v;
}

// in-place: v = v * dinv[row]
__global__ void k_scale(float4* __restrict__ acc,
                        const float* __restrict__ dinv, int n4) {
  int i = blockIdx.x * blockDim.x + threadIdx.x;
  if (i >= n4) return;
  const float dv = dinv[i >> 5];
  float4 v = acc[i];
  v.x *= dv; v.y *= dv; v.z *= dv; v.w *= dv;
  acc[i] = v;
}

extern "C" void kernel_launch(void* const* d_in, const int* in_sizes, int n_in,
                              void* d_out, int out_size, void* d_ws, size_t ws_size,
                              hipStream_t stream) {
  const float* x  = (const float*)d_in[0];
  const int*   ei = (const int*)d_in[1];   // edge_index as int32 per harness convention
  const float* W1 = (const float*)d_in[2];
  const float* b1 = (const float*)d_in[3];
  const float* W2 = (const float*)d_in[4];
  const float* b2 = (const float*)d_in[5];

  const int N = in_sizes[0] / F;       // 50000
  const int E = in_sizes[1] / 2;       // 1600000
  const int* src = ei;
  const int* dst = ei + E;

  char* ws = (char*)d_ws;
  float* dinv = (float*)ws;                                  // 50000 f32
  float* hbuf = (float*)(ws + (1u << 20));                   // N*F f32
  float* acc1 = (float*)(ws + (1u << 20) + (size_t)N * F * 4); // N*F f32
  float* out  = (float*)d_out;                               // layer-2 accumulator

  const int B = 256;
  const int nodeBlocks = (N + B - 1) / B;
  const int edgeBlocks = (E + B - 1) / B;
  const int scatBlocks = (E * 32 + B - 1) / B;
  const int n4 = N * (F / 4);
  const int n4Blocks = (n4 + B - 1) / B;
  const int gemmBlocks = (N + 1) / 2;

  // degree -> dinv
  k_deg_init<<<nodeBlocks, B, 0, stream>>>(dinv, N);
  k_deg_count<<<edgeBlocks, B, 0, stream>>>(dst, E, dinv);
  k_dinv<<<nodeBlocks, B, 0, stream>>>(dinv, N);

  // layer 1
  k_linear_scale<<<gemmBlocks, B, 0, stream>>>(x, W1, b1, dinv, hbuf, acc1, N);
  k_scatter<<<scatBlocks, B, 0, stream>>>(src, dst, E, hbuf, acc1);
  k_relu_scale<<<n4Blocks, B, 0, stream>>>((float4*)acc1, dinv, n4);  // acc1 -> X2

  // layer 2
  k_linear_scale<<<gemmBlocks, B, 0, stream>>>(acc1, W2, b2, dinv, hbuf, out, N);
  k_scatter<<<scatBlocks, B, 0, stream>>>(src, dst, E, hbuf, out);
  k_scale<<<n4Blocks, B, 0, stream>>>((float4*)out, dinv, n4);
}

// Round 2
// 1119.741 us; speedup vs baseline: 5.5236x; 5.5236x over previous
//
#include <hip/hip_runtime.h>

// GCN 2-layer forward, N=50000, F=128, E=1.6M (+ self loops).
//
//   h'   = (x @ W^T + b) * dinv[row]
//   out  = dinv[row] * (h'[row] + sum_{e: dst=row} h'[src[e]])   (+ relu L1)
//
// Pull-mode aggregation over on-device CSR (counting sort) -- no f32 atomics.
//
// ws layout:
//   [0]        dinv    N f32      (200 KB)
//   [256K]     deg     N i32
//   [512K]     rowptr  N+1 i32
//   [768K]     cursor  N i32
//   [1M-4K]    bsums   256 i32
//   [1M]       csr_src E i32      (6.4 MB)
//   [8M]       hbuf    N*F f32    (25.6 MB)
//   [34M]      xbuf2   N*F f32    (25.6 MB)

static constexpr int F = 128;

__global__ void k_zero_i32(int* __restrict__ p, int n) {
  int i = blockIdx.x * blockDim.x + threadIdx.x;
  if (i < n) p[i] = 0;
}

__global__ void k_count(const int* __restrict__ dst, int E,
                        int* __restrict__ deg) {
  int i = blockIdx.x * blockDim.x + threadIdx.x;
  if (i < E) atomicAdd(&deg[dst[i]], 1);
}

__global__ void k_dinv(const int* __restrict__ deg, float* __restrict__ dinv,
                       int n) {
  int i = blockIdx.x * blockDim.x + threadIdx.x;
  if (i < n) dinv[i] = rsqrtf((float)(deg[i] + 1));  // +1 self loop
}

// block-level exclusive scan (256 elems/block), Hillis-Steele in LDS
__global__ __launch_bounds__(256) void k_scan1(const int* __restrict__ deg,
                                               int n, int* __restrict__ rowptr,
                                               int* __restrict__ bsums) {
  __shared__ int s[256];
  const int t = threadIdx.x;
  const int i = blockIdx.x * 256 + t;
  const int v = (i < n) ? deg[i] : 0;
  s[t] = v;
  __syncthreads();
#pragma unroll
  for (int off = 1; off < 256; off <<= 1) {
    int add = (t >= off) ? s[t - off] : 0;
    __syncthreads();
    s[t] += add;
    __syncthreads();
  }
  if (i < n) rowptr[i] = s[t] - v;          // exclusive within block
  if (t == 255) bsums[blockIdx.x] = s[255]; // block total
}

// scan the (<=256) block sums in one block, in place -> exclusive
__global__ __launch_bounds__(256) void k_scan2(int* __restrict__ bsums, int nb) {
  __shared__ int s[256];
  const int t = threadIdx.x;
  const int v = (t < nb) ? bsums[t] : 0;
  s[t] = v;
  __syncthreads();
#pragma unroll
  for (int off = 1; off < 256; off <<= 1) {
    int add = (t >= off) ? s[t - off] : 0;
    __syncthreads();
    s[t] += add;
    __syncthreads();
  }
  if (t < nb) bsums[t] = s[t] - v;
}

__global__ void k_scan3(int* __restrict__ rowptr, const int* __restrict__ bsums,
                        int* __restrict__ cursor, int n, int E) {
  int i = blockIdx.x * blockDim.x + threadIdx.x;
  if (i < n) {
    int r = rowptr[i] + bsums[i >> 8];
    rowptr[i] = r;
    cursor[i] = r;
    if (i == 0) rowptr[n] = E;
  }
}

__global__ void k_fill(const int* __restrict__ src, const int* __restrict__ dst,
                       int E, int* __restrict__ cursor,
                       int* __restrict__ csr_src) {
  int e = blockIdx.x * blockDim.x + threadIdx.x;
  if (e < E) {
    int pos = atomicAdd(&cursor[dst[e]], 1);
    csr_src[pos] = src[e];
  }
}

// hout[row,:] = (in[row,:] @ W^T + bias) * dinv[row]
__global__ __launch_bounds__(256) void k_linear_scale(
    const float* __restrict__ in, const float* __restrict__ W,
    const float* __restrict__ bias, const float* __restrict__ dinv,
    float* __restrict__ hout, int n) {
  const int half = threadIdx.x >> 7;  // 2 rows per block
  const int j = threadIdx.x & (F - 1);
  const int row = blockIdx.x * 2 + half;
  __shared__ float xs[2][F];
  if (row < n) xs[half][j] = in[row * F + j];
  __syncthreads();
  if (row >= n) return;
  const float4* __restrict__ Wr = (const float4*)(W + j * F);
  const float4* __restrict__ xr = (const float4*)(xs[half]);
  float s = 0.f;
#pragma unroll
  for (int k = 0; k < F / 4; ++k) {
    const float4 w = Wr[k];
    const float4 xv = xr[k];
    s += w.x * xv.x + w.y * xv.y + w.z * xv.z + w.w * xv.w;
  }
  hout[row * F + j] = (s + bias[j]) * dinv[row];
}

// one 64-lane wave per node: acc = h[row] + sum h[csr_src[k]]; scale (+relu)
template <bool RELU>
__global__ __launch_bounds__(256) void k_pull(
    const int* __restrict__ rowptr, const int* __restrict__ csr,
    const float* __restrict__ h, const float* __restrict__ dinv,
    float* __restrict__ out, int n) {
  const int wid = (blockIdx.x * blockDim.x + threadIdx.x) >> 6;
  if (wid >= n) return;
  const int lane = threadIdx.x & 63;
  const float2* __restrict__ hv = (const float2*)h;
  const int beg = rowptr[wid];
  const int end = rowptr[wid + 1];
  float2 acc = hv[(size_t)wid * 64 + lane];  // self loop
  int k = beg;
  for (; k + 4 <= end; k += 4) {
    const int s0 = csr[k], s1 = csr[k + 1], s2 = csr[k + 2], s3 = csr[k + 3];
    const float2 v0 = hv[(size_t)s0 * 64 + lane];
    const float2 v1 = hv[(size_t)s1 * 64 + lane];
    const float2 v2 = hv[(size_t)s2 * 64 + lane];
    const float2 v3 = hv[(size_t)s3 * 64 + lane];
    acc.x += v0.x + v1.x + v2.x + v3.x;
    acc.y += v0.y + v1.y + v2.y + v3.y;
  }
  for (; k < end; ++k) {
    const int s = csr[k];
    const float2 v = hv[(size_t)s * 64 + lane];
    acc.x += v.x;
    acc.y += v.y;
  }
  const float dv = dinv[wid];
  acc.x *= dv;
  acc.y *= dv;
  if (RELU) {
    acc.x = fmaxf(acc.x, 0.f);
    acc.y = fmaxf(acc.y, 0.f);
  }
  ((float2*)out)[(size_t)wid * 64 + lane] = acc;
}

extern "C" void kernel_launch(void* const* d_in, const int* in_sizes, int n_in,
                              void* d_out, int out_size, void* d_ws, size_t ws_size,
                              hipStream_t stream) {
  const float* x  = (const float*)d_in[0];
  const int*   ei = (const int*)d_in[1];
  const float* W1 = (const float*)d_in[2];
  const float* b1 = (const float*)d_in[3];
  const float* W2 = (const float*)d_in[4];
  const float* b2 = (const float*)d_in[5];

  const int N = in_sizes[0] / F;  // 50000
  const int E = in_sizes[1] / 2;  // 1600000
  const int* src = ei;
  const int* dst = ei + E;

  char* ws = (char*)d_ws;
  float* dinv   = (float*)(ws);
  int*   deg    = (int*)(ws + (256u << 10));
  int*   rowptr = (int*)(ws + (512u << 10));
  int*   cursor = (int*)(ws + (768u << 10));
  int*   bsums  = (int*)(ws + (1u << 20) - 4096);
  int*   csr    = (int*)(ws + (1u << 20));
  float* hbuf   = (float*)(ws + (8u << 20));
  float* xbuf2  = (float*)(ws + (8u << 20) + (size_t)N * F * 4);
  float* out    = (float*)d_out;

  const int B = 256;
  const int nodeBlocks = (N + B - 1) / B;       // 196
  const int edgeBlocks = (E + B - 1) / B;
  const int gemmBlocks = (N + 1) / 2;
  const int pullBlocks = (N * 64 + B - 1) / B;  // 12500

  // CSR build + dinv
  k_zero_i32<<<nodeBlocks, B, 0, stream>>>(deg, N);
  k_count<<<edgeBlocks, B, 0, stream>>>(dst, E, deg);
  k_dinv<<<nodeBlocks, B, 0, stream>>>(deg, dinv, N);
  k_scan1<<<nodeBlocks, B, 0, stream>>>(deg, N, rowptr, bsums);
  k_scan2<<<1, B, 0, stream>>>(bsums, nodeBlocks);
  k_scan3<<<nodeBlocks, B, 0, stream>>>(rowptr, bsums, cursor, N, E);
  k_fill<<<edgeBlocks, B, 0, stream>>>(src, dst, E, cursor, csr);

  // layer 1
  k_linear_scale<<<gemmBlocks, B, 0, stream>>>(x, W1, b1, dinv, hbuf, N);
  k_pull<true><<<pullBlocks, B, 0, stream>>>(rowptr, csr, hbuf, dinv, xbuf2, N);

  // layer 2
  k_linear_scale<<<gemmBlocks, B, 0, stream>>>(xbuf2, W2, b2, dinv, hbuf, N);
  k_pull<false><<<pullBlocks, B, 0, stream>>>(rowptr, csr, hbuf, dinv, out, N);
}

// Round 3
// 484.383 us; speedup vs baseline: 12.7689x; 2.3117x over previous
//
#include <hip/hip_runtime.h>

// GCN 2-layer forward, N=50000, F=128, E=1.6M (+ self loops).
//
//   h'   = (x @ W^T + b) * dinv[row]
//   out  = dinv[row] * (h'[row] + sum_{e: dst=row} h'[src[e]])   (+ relu L1)
//
// Pull-mode aggregation over on-device CSR (counting sort) -- no f32 atomics.
// GEMM: register-tiled VALU SGEMM (no f32 MFMA on CDNA4), 64x128 block tile,
// 8x4 per-thread micro-tile, A and W staged transposed in LDS.
//
// ws layout:
//   [0]        dinv    N f32      (200 KB)
//   [256K]     deg     N i32
//   [512K]     rowptr  N+1 i32
//   [768K]     cursor  N i32
//   [1M-4K]    bsums   256 i32
//   [1M]       csr_src E i32      (6.4 MB)
//   [8M]       hbuf    N*F f32    (25.6 MB)
//   [34M]      xbuf2   N*F f32    (25.6 MB)

static constexpr int F = 128;

__global__ void k_zero_i32(int* __restrict__ p, int n) {
  int i = blockIdx.x * blockDim.x + threadIdx.x;
  if (i < n) p[i] = 0;
}

__global__ void k_count(const int* __restrict__ dst, int E,
                        int* __restrict__ deg) {
  int i = blockIdx.x * blockDim.x + threadIdx.x;
  if (i < E) atomicAdd(&deg[dst[i]], 1);
}

__global__ void k_dinv(const int* __restrict__ deg, float* __restrict__ dinv,
                       int n) {
  int i = blockIdx.x * blockDim.x + threadIdx.x;
  if (i < n) dinv[i] = rsqrtf((float)(deg[i] + 1));  // +1 self loop
}

// block-level exclusive scan (256 elems/block), Hillis-Steele in LDS
__global__ __launch_bounds__(256) void k_scan1(const int* __restrict__ deg,
                                               int n, int* __restrict__ rowptr,
                                               int* __restrict__ bsums) {
  __shared__ int s[256];
  const int t = threadIdx.x;
  const int i = blockIdx.x * 256 + t;
  const int v = (i < n) ? deg[i] : 0;
  s[t] = v;
  __syncthreads();
#pragma unroll
  for (int off = 1; off < 256; off <<= 1) {
    int add = (t >= off) ? s[t - off] : 0;
    __syncthreads();
    s[t] += add;
    __syncthreads();
  }
  if (i < n) rowptr[i] = s[t] - v;          // exclusive within block
  if (t == 255) bsums[blockIdx.x] = s[255]; // block total
}

// scan the (<=256) block sums in one block, in place -> exclusive
__global__ __launch_bounds__(256) void k_scan2(int* __restrict__ bsums, int nb) {
  __shared__ int s[256];
  const int t = threadIdx.x;
  const int v = (t < nb) ? bsums[t] : 0;
  s[t] = v;
  __syncthreads();
#pragma unroll
  for (int off = 1; off < 256; off <<= 1) {
    int add = (t >= off) ? s[t - off] : 0;
    __syncthreads();
    s[t] += add;
    __syncthreads();
  }
  if (t < nb) bsums[t] = s[t] - v;
}

__global__ void k_scan3(int* __restrict__ rowptr, const int* __restrict__ bsums,
                        int* __restrict__ cursor, int n, int E) {
  int i = blockIdx.x * blockDim.x + threadIdx.x;
  if (i < n) {
    int r = rowptr[i] + bsums[i >> 8];
    rowptr[i] = r;
    cursor[i] = r;
    if (i == 0) rowptr[n] = E;
  }
}

__global__ void k_fill(const int* __restrict__ src, const int* __restrict__ dst,
                       int E, int* __restrict__ cursor,
                       int* __restrict__ csr_src) {
  int e = blockIdx.x * blockDim.x + threadIdx.x;
  if (e < E) {
    int pos = atomicAdd(&cursor[dst[e]], 1);
    csr_src[pos] = src[e];
  }
}

// hout[m,:] = (A[m,:] @ W^T + bias) * dinv[m]
// block tile 64x128, thread micro-tile 8x4, K tiled by 32.
static constexpr int ASTR = 68;   // 64 + 4 pad (keeps 16B alignment)
static constexpr int BSTR = 132;  // 128 + 4 pad

__global__ __launch_bounds__(256) void k_gemm(
    const float* __restrict__ A, const float* __restrict__ W,
    const float* __restrict__ bias, const float* __restrict__ dinv,
    float* __restrict__ hout, int n) {
  __shared__ float As[32][ASTR];  // [k][m]  (transposed)
  __shared__ float Bs[32][BSTR];  // [k][n]  (W transposed)
  const int tid = threadIdx.x;
  const int tm = tid >> 5;  // 0..7  -> rows  tm*8 .. tm*8+7
  const int tn = tid & 31;  // 0..31 -> cols  tn*4 .. tn*4+3
  const int m0 = blockIdx.x * 64;

  float acc[8][4];
#pragma unroll
  for (int i = 0; i < 8; ++i)
#pragma unroll
    for (int j = 0; j < 4; ++j) acc[i][j] = 0.f;

  for (int kt = 0; kt < F; kt += 32) {
    __syncthreads();
    // stage A tile (64 rows x 32 k), transposed: 2 float4 per thread
#pragma unroll
    for (int l = 0; l < 2; ++l) {
      const int idx = tid + l * 256;
      const int r = idx >> 3;       // 0..63
      const int j = idx & 7;        // 0..7 -> k offset j*4
      const int grow = m0 + r;
      float4 v = make_float4(0.f, 0.f, 0.f, 0.f);
      if (grow < n) v = *(const float4*)(A + (size_t)grow * F + kt + j * 4);
      As[j * 4 + 0][r] = v.x;
      As[j * 4 + 1][r] = v.y;
      As[j * 4 + 2][r] = v.z;
      As[j * 4 + 3][r] = v.w;
    }
    // stage W tile (128 rows x 32 k), transposed: 4 float4 per thread
#pragma unroll
    for (int l = 0; l < 4; ++l) {
      const int idx = tid + l * 256;
      const int r = idx >> 3;       // 0..127 (output col)
      const int j = idx & 7;
      const float4 v = *(const float4*)(W + (size_t)r * F + kt + j * 4);
      Bs[j * 4 + 0][r] = v.x;
      Bs[j * 4 + 1][r] = v.y;
      Bs[j * 4 + 2][r] = v.z;
      Bs[j * 4 + 3][r] = v.w;
    }
    __syncthreads();
#pragma unroll
    for (int k = 0; k < 32; ++k) {
      const float4 a0 = *(const float4*)&As[k][tm * 8];
      const float4 a1 = *(const float4*)&As[k][tm * 8 + 4];
      const float4 b = *(const float4*)&Bs[k][tn * 4];
      acc[0][0] += a0.x * b.x; acc[0][1] += a0.x * b.y; acc[0][2] += a0.x * b.z; acc[0][3] += a0.x * b.w;
      acc[1][0] += a0.y * b.x; acc[1][1] += a0.y * b.y; acc[1][2] += a0.y * b.z; acc[1][3] += a0.y * b.w;
      acc[2][0] += a0.z * b.x; acc[2][1] += a0.z * b.y; acc[2][2] += a0.z * b.z; acc[2][3] += a0.z * b.w;
      acc[3][0] += a0.w * b.x; acc[3][1] += a0.w * b.y; acc[3][2] += a0.w * b.z; acc[3][3] += a0.w * b.w;
      acc[4][0] += a1.x * b.x; acc[4][1] += a1.x * b.y; acc[4][2] += a1.x * b.z; acc[4][3] += a1.x * b.w;
      acc[5][0] += a1.y * b.x; acc[5][1] += a1.y * b.y; acc[5][2] += a1.y * b.z; acc[5][3] += a1.y * b.w;
      acc[6][0] += a1.z * b.x; acc[6][1] += a1.z * b.y; acc[6][2] += a1.z * b.z; acc[6][3] += a1.z * b.w;
      acc[7][0] += a1.w * b.x; acc[7][1] += a1.w * b.y; acc[7][2] += a1.w * b.z; acc[7][3] += a1.w * b.w;
    }
  }

  const float4 bv = *(const float4*)(bias + tn * 4);
#pragma unroll
  for (int i = 0; i < 8; ++i) {
    const int grow = m0 + tm * 8 + i;
    if (grow < n) {
      const float dv = dinv[grow];
      float4 o;
      o.x = (acc[i][0] + bv.x) * dv;
      o.y = (acc[i][1] + bv.y) * dv;
      o.z = (acc[i][2] + bv.z) * dv;
      o.w = (acc[i][3] + bv.w) * dv;
      *(float4*)(hout + (size_t)grow * F + tn * 4) = o;
    }
  }
}

// one 64-lane wave per node: acc = h[row] + sum h[csr_src[k]]; scale (+relu)
template <bool RELU>
__global__ __launch_bounds__(256) void k_pull(
    const int* __restrict__ rowptr, const int* __restrict__ csr,
    const float* __restrict__ h, const float* __restrict__ dinv,
    float* __restrict__ out, int n) {
  const int wid = (blockIdx.x * blockDim.x + threadIdx.x) >> 6;
  if (wid >= n) return;
  const int lane = threadIdx.x & 63;
  const float2* __restrict__ hv = (const float2*)h;
  const int beg = rowptr[wid];
  const int end = rowptr[wid + 1];
  float2 acc = hv[(size_t)wid * 64 + lane];  // self loop
  int k = beg;
  for (; k + 4 <= end; k += 4) {
    const int s0 = csr[k], s1 = csr[k + 1], s2 = csr[k + 2], s3 = csr[k + 3];
    const float2 v0 = hv[(size_t)s0 * 64 + lane];
    const float2 v1 = hv[(size_t)s1 * 64 + lane];
    const float2 v2 = hv[(size_t)s2 * 64 + lane];
    const float2 v3 = hv[(size_t)s3 * 64 + lane];
    acc.x += v0.x + v1.x + v2.x + v3.x;
    acc.y += v0.y + v1.y + v2.y + v3.y;
  }
  for (; k < end; ++k) {
    const int s = csr[k];
    const float2 v = hv[(size_t)s * 64 + lane];
    acc.x += v.x;
    acc.y += v.y;
  }
  const float dv = dinv[wid];
  acc.x *= dv;
  acc.y *= dv;
  if (RELU) {
    acc.x = fmaxf(acc.x, 0.f);
    acc.y = fmaxf(acc.y, 0.f);
  }
  ((float2*)out)[(size_t)wid * 64 + lane] = acc;
}

extern "C" void kernel_launch(void* const* d_in, const int* in_sizes, int n_in,
                              void* d_out, int out_size, void* d_ws, size_t ws_size,
                              hipStream_t stream) {
  const float* x  = (const float*)d_in[0];
  const int*   ei = (const int*)d_in[1];
  const float* W1 = (const float*)d_in[2];
  const float* b1 = (const float*)d_in[3];
  const float* W2 = (const float*)d_in[4];
  const float* b2 = (const float*)d_in[5];

  const int N = in_sizes[0] / F;  // 50000
  const int E = in_sizes[1] / 2;  // 1600000
  const int* src = ei;
  const int* dst = ei + E;

  char* ws = (char*)d_ws;
  float* dinv   = (float*)(ws);
  int*   deg    = (int*)(ws + (256u << 10));
  int*   rowptr = (int*)(ws + (512u << 10));
  int*   cursor = (int*)(ws + (768u << 10));
  int*   bsums  = (int*)(ws + (1u << 20) - 4096);
  int*   csr    = (int*)(ws + (1u << 20));
  float* hbuf   = (float*)(ws + (8u << 20));
  float* xbuf2  = (float*)(ws + (8u << 20) + (size_t)N * F * 4);
  float* out    = (float*)d_out;

  const int B = 256;
  const int nodeBlocks = (N + B - 1) / B;       // 196
  const int edgeBlocks = (E + B - 1) / B;
  const int gemmBlocks = (N + 63) / 64;         // 782
  const int pullBlocks = (N * 64 + B - 1) / B;  // 12500

  // CSR build + dinv
  k_zero_i32<<<nodeBlocks, B, 0, stream>>>(deg, N);
  k_count<<<edgeBlocks, B, 0, stream>>>(dst, E, deg);
  k_dinv<<<nodeBlocks, B, 0, stream>>>(deg, dinv, N);
  k_scan1<<<nodeBlocks, B, 0, stream>>>(deg, N, rowptr, bsums);
  k_scan2<<<1, B, 0, stream>>>(bsums, nodeBlocks);
  k_scan3<<<nodeBlocks, B, 0, stream>>>(rowptr, bsums, cursor, N, E);
  k_fill<<<edgeBlocks, B, 0, stream>>>(src, dst, E, cursor, csr);

  // layer 1
  k_gemm<<<gemmBlocks, B, 0, stream>>>(x, W1, b1, dinv, hbuf, N);
  k_pull<true><<<pullBlocks, B, 0, stream>>>(rowptr, csr, hbuf, dinv, xbuf2, N);

  // layer 2
  k_gemm<<<gemmBlocks, B, 0, stream>>>(xbuf2, W2, b2, dinv, hbuf, N);
  k_pull<false><<<pullBlocks, B, 0, stream>>>(rowptr, csr, hbuf, dinv, out, N);
}

// Round 4
// 329.369 us; speedup vs baseline: 18.7785x; 1.4706x over previous
//
#include <hip/hip_runtime.h>

// GCN 2-layer forward, N=50000, F=128, E=1.6M (+ self loops).
//
//   h'   = (x @ W^T + b) * dinv[row]
//   out  = dinv[row] * (h'[row] + sum_{e: dst=row} h'[src[e]])   (+ relu L1)
//
// CSR built via two-level counting sort (LDS atomics only, coalesced writes):
//   k_hist  : per-chunk LDS histogram over 128-node ranges -> rtot
//   k_scanR : scan range totals -> rbase, seed gcur
//   k_part  : place packed edges (dstLocal<<16|src) range-sorted (chunk-contig)
//   k_fillR : per-range LDS count/scan -> rowptr+dinv, LDS-cursor fill of csr
// Pull-mode aggregation (wave per node). GEMM: register-tiled VALU SGEMM.
//
// ws layout:
//   [0]     rtot    R i32
//   [4K]    rbase   R+1 i32
//   [8K]    gcur    R i32
//   [16K]   dinv    N f32    (200 KB)
//   [256K]  rowptr  N+1 i32
//   [1M]    rsorted E u32    (6.4 MB)
//   [8M]    csr     E i32    (6.4 MB)
//   [16M]   hbuf    N*F f32  (25.6 MB)
// d_out doubles as the layer-1 aggregation output (fully overwritten later).

static constexpr int F = 128;
static constexpr int NR = 128;   // nodes per range (dst>>7)
static constexpr int CH = 4096;  // edges per chunk
static constexpr int RMAX = 512; // max ranges supported (N < 65536)

__global__ void k_zero_i32(int* __restrict__ p, int n) {
  int i = blockIdx.x * blockDim.x + threadIdx.x;
  if (i < n) p[i] = 0;
}

__global__ __launch_bounds__(256) void k_hist(const int* __restrict__ dst,
                                              int E, int R,
                                              int* __restrict__ rtot) {
  __shared__ int h[RMAX];
  for (int i = threadIdx.x; i < R; i += 256) h[i] = 0;
  __syncthreads();
  const int e0 = blockIdx.x * CH;
  const int e1 = min(e0 + CH, E);
  for (int i = e0 + threadIdx.x; i < e1; i += 256)
    atomicAdd(&h[dst[i] >> 7], 1);
  __syncthreads();
  for (int i = threadIdx.x; i < R; i += 256)
    if (h[i]) atomicAdd(&rtot[i], h[i]);
}

__global__ __launch_bounds__(512) void k_scanR(const int* __restrict__ rtot,
                                               int R, int E,
                                               int* __restrict__ rbase,
                                               int* __restrict__ gcur) {
  __shared__ int s[512];
  const int t = threadIdx.x;
  const int v = (t < R) ? rtot[t] : 0;
  s[t] = v;
  __syncthreads();
#pragma unroll
  for (int off = 1; off < 512; off <<= 1) {
    int a = (t >= off) ? s[t - off] : 0;
    __syncthreads();
    s[t] += a;
    __syncthreads();
  }
  if (t < R) {
    const int b = s[t] - v;  // exclusive
    rbase[t] = b;
    gcur[t] = b;
  }
  if (t == 0) rbase[R] = E;
}

__global__ __launch_bounds__(256) void k_part(const int* __restrict__ src,
                                              const int* __restrict__ dst,
                                              int E, int R,
                                              int* __restrict__ gcur,
                                              unsigned* __restrict__ rsorted) {
  __shared__ int h[RMAX];
  __shared__ int cur[RMAX];
  for (int i = threadIdx.x; i < R; i += 256) h[i] = 0;
  __syncthreads();
  const int e0 = blockIdx.x * CH;
  const int e1 = min(e0 + CH, E);
  for (int i = e0 + threadIdx.x; i < e1; i += 256)
    atomicAdd(&h[dst[i] >> 7], 1);
  __syncthreads();
  for (int i = threadIdx.x; i < R; i += 256)
    cur[i] = h[i] ? atomicAdd(&gcur[i], h[i]) : 0;
  __syncthreads();
  for (int i = e0 + threadIdx.x; i < e1; i += 256) {
    const int d = dst[i];
    const int s = src[i];
    const int pos = atomicAdd(&cur[d >> 7], 1);
    rsorted[pos] = ((unsigned)(d & (NR - 1)) << 16) | (unsigned)s;
  }
}

__global__ __launch_bounds__(256) void k_fillR(
    const unsigned* __restrict__ rsorted, const int* __restrict__ rbase,
    int N, int E, int* __restrict__ rowptr, float* __restrict__ dinv,
    int* __restrict__ csr) {
  __shared__ int cnt[NR];
  __shared__ int sc[NR];
  __shared__ int cur[NR];
  const int r = blockIdx.x;
  const int tid = threadIdx.x;
  const int b = rbase[r];
  const int e = rbase[r + 1];
  if (tid < NR) cnt[tid] = 0;
  __syncthreads();
  for (int i = b + tid; i < e; i += 256)
    atomicAdd(&cnt[rsorted[i] >> 16], 1);
  __syncthreads();
  if (tid < NR) sc[tid] = cnt[tid];
  __syncthreads();
#pragma unroll
  for (int off = 1; off < NR; off <<= 1) {
    int a = (tid < NR && tid >= off) ? sc[tid - off] : 0;
    __syncthreads();
    if (tid < NR) sc[tid] += a;
    __syncthreads();
  }
  if (tid < NR) {
    const int excl = sc[tid] - cnt[tid];
    cur[tid] = excl;
    const int node = r * NR + tid;
    if (node < N) {
      rowptr[node] = b + excl;
      dinv[node] = rsqrtf((float)(cnt[tid] + 1));  // +1 self loop
    }
  }
  if (r == 0 && tid == 0) rowptr[N] = E;
  __syncthreads();
  for (int i = b + tid; i < e; i += 256) {
    const unsigned v = rsorted[i];
    const int pos = b + atomicAdd(&cur[v >> 16], 1);
    csr[pos] = (int)(v & 0xFFFFu);
  }
}

// hout[m,:] = (A[m,:] @ W^T + bias) * dinv[m]
// block tile 64x128, thread micro-tile 8x4, K tiled by 32.
static constexpr int ASTR = 68;   // 64 + 4 pad (keeps 16B alignment)
static constexpr int BSTR = 132;  // 128 + 4 pad

__global__ __launch_bounds__(256) void k_gemm(
    const float* __restrict__ A, const float* __restrict__ W,
    const float* __restrict__ bias, const float* __restrict__ dinv,
    float* __restrict__ hout, int n) {
  __shared__ float As[32][ASTR];  // [k][m]  (transposed)
  __shared__ float Bs[32][BSTR];  // [k][n]  (W transposed)
  const int tid = threadIdx.x;
  const int tm = tid >> 5;  // 0..7  -> rows  tm*8 .. tm*8+7
  const int tn = tid & 31;  // 0..31 -> cols  tn*4 .. tn*4+3
  const int m0 = blockIdx.x * 64;

  float acc[8][4];
#pragma unroll
  for (int i = 0; i < 8; ++i)
#pragma unroll
    for (int j = 0; j < 4; ++j) acc[i][j] = 0.f;

  for (int kt = 0; kt < F; kt += 32) {
    __syncthreads();
#pragma unroll
    for (int l = 0; l < 2; ++l) {
      const int idx = tid + l * 256;
      const int r = idx >> 3;
      const int j = idx & 7;
      const int grow = m0 + r;
      float4 v = make_float4(0.f, 0.f, 0.f, 0.f);
      if (grow < n) v = *(const float4*)(A + (size_t)grow * F + kt + j * 4);
      As[j * 4 + 0][r] = v.x;
      As[j * 4 + 1][r] = v.y;
      As[j * 4 + 2][r] = v.z;
      As[j * 4 + 3][r] = v.w;
    }
#pragma unroll
    for (int l = 0; l < 4; ++l) {
      const int idx = tid + l * 256;
      const int r = idx >> 3;
      const int j = idx & 7;
      const float4 v = *(const float4*)(W + (size_t)r * F + kt + j * 4);
      Bs[j * 4 + 0][r] = v.x;
      Bs[j * 4 + 1][r] = v.y;
      Bs[j * 4 + 2][r] = v.z;
      Bs[j * 4 + 3][r] = v.w;
    }
    __syncthreads();
#pragma unroll
    for (int k = 0; k < 32; ++k) {
      const float4 a0 = *(const float4*)&As[k][tm * 8];
      const float4 a1 = *(const float4*)&As[k][tm * 8 + 4];
      const float4 b = *(const float4*)&Bs[k][tn * 4];
      acc[0][0] += a0.x * b.x; acc[0][1] += a0.x * b.y; acc[0][2] += a0.x * b.z; acc[0][3] += a0.x * b.w;
      acc[1][0] += a0.y * b.x; acc[1][1] += a0.y * b.y; acc[1][2] += a0.y * b.z; acc[1][3] += a0.y * b.w;
      acc[2][0] += a0.z * b.x; acc[2][1] += a0.z * b.y; acc[2][2] += a0.z * b.z; acc[2][3] += a0.z * b.w;
      acc[3][0] += a0.w * b.x; acc[3][1] += a0.w * b.y; acc[3][2] += a0.w * b.z; acc[3][3] += a0.w * b.w;
      acc[4][0] += a1.x * b.x; acc[4][1] += a1.x * b.y; acc[4][2] += a1.x * b.z; acc[4][3] += a1.x * b.w;
      acc[5][0] += a1.y * b.x; acc[5][1] += a1.y * b.y; acc[5][2] += a1.y * b.z; acc[5][3] += a1.y * b.w;
      acc[6][0] += a1.z * b.x; acc[6][1] += a1.z * b.y; acc[6][2] += a1.z * b.z; acc[6][3] += a1.z * b.w;
      acc[7][0] += a1.w * b.x; acc[7][1] += a1.w * b.y; acc[7][2] += a1.w * b.z; acc[7][3] += a1.w * b.w;
    }
  }

  const float4 bv = *(const float4*)(bias + tn * 4);
#pragma unroll
  for (int i = 0; i < 8; ++i) {
    const int grow = m0 + tm * 8 + i;
    if (grow < n) {
      const float dv = dinv[grow];
      float4 o;
      o.x = (acc[i][0] + bv.x) * dv;
      o.y = (acc[i][1] + bv.y) * dv;
      o.z = (acc[i][2] + bv.z) * dv;
      o.w = (acc[i][3] + bv.w) * dv;
      *(float4*)(hout + (size_t)grow * F + tn * 4) = o;
    }
  }
}

// one 64-lane wave per node: acc = h[row] + sum h[csr_src[k]]; scale (+relu)
template <bool RELU>
__global__ __launch_bounds__(256) void k_pull(
    const int* __restrict__ rowptr, const int* __restrict__ csr,
    const float* __restrict__ h, const float* __restrict__ dinv,
    float* __restrict__ out, int n) {
  const int wid = (blockIdx.x * blockDim.x + threadIdx.x) >> 6;
  if (wid >= n) return;
  const int lane = threadIdx.x & 63;
  const float2* __restrict__ hv = (const float2*)h;
  const int beg = rowptr[wid];
  const int end = rowptr[wid + 1];
  float2 acc = hv[(size_t)wid * 64 + lane];  // self loop
  int k = beg;
  for (; k + 4 <= end; k += 4) {
    const int s0 = csr[k], s1 = csr[k + 1], s2 = csr[k + 2], s3 = csr[k + 3];
    const float2 v0 = hv[(size_t)s0 * 64 + lane];
    const float2 v1 = hv[(size_t)s1 * 64 + lane];
    const float2 v2 = hv[(size_t)s2 * 64 + lane];
    const float2 v3 = hv[(size_t)s3 * 64 + lane];
    acc.x += v0.x + v1.x + v2.x + v3.x;
    acc.y += v0.y + v1.y + v2.y + v3.y;
  }
  for (; k < end; ++k) {
    const int s = csr[k];
    const float2 v = hv[(size_t)s * 64 + lane];
    acc.x += v.x;
    acc.y += v.y;
  }
  const float dv = dinv[wid];
  acc.x *= dv;
  acc.y *= dv;
  if (RELU) {
    acc.x = fmaxf(acc.x, 0.f);
    acc.y = fmaxf(acc.y, 0.f);
  }
  ((float2*)out)[(size_t)wid * 64 + lane] = acc;
}

extern "C" void kernel_launch(void* const* d_in, const int* in_sizes, int n_in,
                              void* d_out, int out_size, void* d_ws, size_t ws_size,
                              hipStream_t stream) {
  const float* x  = (const float*)d_in[0];
  const int*   ei = (const int*)d_in[1];
  const float* W1 = (const float*)d_in[2];
  const float* b1 = (const float*)d_in[3];
  const float* W2 = (const float*)d_in[4];
  const float* b2 = (const float*)d_in[5];

  const int N = in_sizes[0] / F;  // 50000
  const int E = in_sizes[1] / 2;  // 1600000
  const int* src = ei;
  const int* dst = ei + E;
  const int R = (N + NR - 1) / NR;  // 391
  const int C = (E + CH - 1) / CH;  // 391

  char* ws = (char*)d_ws;
  int*      rtot    = (int*)(ws);
  int*      rbase   = (int*)(ws + (4u << 10));
  int*      gcur    = (int*)(ws + (8u << 10));
  float*    dinv    = (float*)(ws + (16u << 10));
  int*      rowptr  = (int*)(ws + (256u << 10));
  unsigned* rsorted = (unsigned*)(ws + (1u << 20));
  int*      csr     = (int*)(ws + (8u << 20));
  float*    hbuf    = (float*)(ws + (16u << 20));
  float*    out     = (float*)d_out;  // also layer-1 aggregation buffer

  const int B = 256;
  const int gemmBlocks = (N + 63) / 64;         // 782
  const int pullBlocks = (N * 64 + B - 1) / B;  // 12500

  // CSR build (counting sort, LDS atomics only)
  k_zero_i32<<<1, 512, 0, stream>>>(rtot, R);
  k_hist<<<C, B, 0, stream>>>(dst, E, R, rtot);
  k_scanR<<<1, 512, 0, stream>>>(rtot, R, E, rbase, gcur);
  k_part<<<C, B, 0, stream>>>(src, dst, E, R, gcur, rsorted);
  k_fillR<<<R, B, 0, stream>>>(rsorted, rbase, N, E, rowptr, dinv, csr);

  // layer 1
  k_gemm<<<gemmBlocks, B, 0, stream>>>(x, W1, b1, dinv, hbuf, N);
  k_pull<true><<<pullBlocks, B, 0, stream>>>(rowptr, csr, hbuf, dinv, out, N);

  // layer 2
  k_gemm<<<gemmBlocks, B, 0, stream>>>(out, W2, b2, dinv, hbuf, N);
  k_pull<false><<<pullBlocks, B, 0, stream>>>(rowptr, csr, hbuf, dinv, out, N);
}

// Round 5
// 328.889 us; speedup vs baseline: 18.8059x; 1.0015x over previous
//
#include <hip/hip_runtime.h>

// GCN 2-layer forward, N=50000, F=128, E=1.6M (+ self loops).
//
//   h'   = (x @ W^T + b) * dinv[row]
//   out  = dinv[row] * (h'[row] + sum_{e: dst=row} h'[src[e]])   (+ relu L1)
//
// CSR built via two-level counting sort (LDS atomics only, coalesced writes).
// Pull-mode aggregation: one wave per node, TWO edges per step (half-wave
// float4 gathers, 8 rows in flight), shfl_xor(32) combine.
// GEMM: register-tiled VALU SGEMM (no f32 MFMA on CDNA4).
//
// ws layout:
//   [0]     rtot    R i32
//   [4K]    rbase   R+1 i32
//   [8K]    gcur    R i32
//   [16K]   dinv    N f32    (200 KB)
//   [256K]  rowptr  N+1 i32
//   [1M]    rsorted E u32    (6.4 MB)
//   [8M]    csr     E i32    (6.4 MB)
//   [16M]   hbuf    N*F f32  (25.6 MB)
// d_out doubles as the layer-1 aggregation output (fully overwritten later).

static constexpr int F = 128;
static constexpr int NR = 128;   // nodes per range (dst>>7)
static constexpr int CH = 4096;  // edges per chunk
static constexpr int RMAX = 512; // max ranges supported (N < 65536)

__global__ void k_zero_i32(int* __restrict__ p, int n) {
  int i = blockIdx.x * blockDim.x + threadIdx.x;
  if (i < n) p[i] = 0;
}

__global__ __launch_bounds__(256) void k_hist(const int* __restrict__ dst,
                                              int E, int R,
                                              int* __restrict__ rtot) {
  __shared__ int h[RMAX];
  for (int i = threadIdx.x; i < R; i += 256) h[i] = 0;
  __syncthreads();
  const int e0 = blockIdx.x * CH;
  const int e1 = min(e0 + CH, E);
  for (int i = e0 + threadIdx.x; i < e1; i += 256)
    atomicAdd(&h[dst[i] >> 7], 1);
  __syncthreads();
  for (int i = threadIdx.x; i < R; i += 256)
    if (h[i]) atomicAdd(&rtot[i], h[i]);
}

__global__ __launch_bounds__(512) void k_scanR(const int* __restrict__ rtot,
                                               int R, int E,
                                               int* __restrict__ rbase,
                                               int* __restrict__ gcur) {
  __shared__ int s[512];
  const int t = threadIdx.x;
  const int v = (t < R) ? rtot[t] : 0;
  s[t] = v;
  __syncthreads();
#pragma unroll
  for (int off = 1; off < 512; off <<= 1) {
    int a = (t >= off) ? s[t - off] : 0;
    __syncthreads();
    s[t] += a;
    __syncthreads();
  }
  if (t < R) {
    const int b = s[t] - v;  // exclusive
    rbase[t] = b;
    gcur[t] = b;
  }
  if (t == 0) rbase[R] = E;
}

__global__ __launch_bounds__(256) void k_part(const int* __restrict__ src,
                                              const int* __restrict__ dst,
                                              int E, int R,
                                              int* __restrict__ gcur,
                                              unsigned* __restrict__ rsorted) {
  __shared__ int h[RMAX];
  __shared__ int cur[RMAX];
  for (int i = threadIdx.x; i < R; i += 256) h[i] = 0;
  __syncthreads();
  const int e0 = blockIdx.x * CH;
  const int e1 = min(e0 + CH, E);
  for (int i = e0 + threadIdx.x; i < e1; i += 256)
    atomicAdd(&h[dst[i] >> 7], 1);
  __syncthreads();
  for (int i = threadIdx.x; i < R; i += 256)
    cur[i] = h[i] ? atomicAdd(&gcur[i], h[i]) : 0;
  __syncthreads();
  for (int i = e0 + threadIdx.x; i < e1; i += 256) {
    const int d = dst[i];
    const int s = src[i];
    const int pos = atomicAdd(&cur[d >> 7], 1);
    rsorted[pos] = ((unsigned)(d & (NR - 1)) << 16) | (unsigned)s;
  }
}

__global__ __launch_bounds__(256) void k_fillR(
    const unsigned* __restrict__ rsorted, const int* __restrict__ rbase,
    int N, int E, int* __restrict__ rowptr, float* __restrict__ dinv,
    int* __restrict__ csr) {
  __shared__ int cnt[NR];
  __shared__ int sc[NR];
  __shared__ int cur[NR];
  const int r = blockIdx.x;
  const int tid = threadIdx.x;
  const int b = rbase[r];
  const int e = rbase[r + 1];
  if (tid < NR) cnt[tid] = 0;
  __syncthreads();
  for (int i = b + tid; i < e; i += 256)
    atomicAdd(&cnt[rsorted[i] >> 16], 1);
  __syncthreads();
  if (tid < NR) sc[tid] = cnt[tid];
  __syncthreads();
#pragma unroll
  for (int off = 1; off < NR; off <<= 1) {
    int a = (tid < NR && tid >= off) ? sc[tid - off] : 0;
    __syncthreads();
    if (tid < NR) sc[tid] += a;
    __syncthreads();
  }
  if (tid < NR) {
    const int excl = sc[tid] - cnt[tid];
    cur[tid] = excl;
    const int node = r * NR + tid;
    if (node < N) {
      rowptr[node] = b + excl;
      dinv[node] = rsqrtf((float)(cnt[tid] + 1));  // +1 self loop
    }
  }
  if (r == 0 && tid == 0) rowptr[N] = E;
  __syncthreads();
  for (int i = b + tid; i < e; i += 256) {
    const unsigned v = rsorted[i];
    const int pos = b + atomicAdd(&cur[v >> 16], 1);
    csr[pos] = (int)(v & 0xFFFFu);
  }
}

// hout[m,:] = (A[m,:] @ W^T + bias) * dinv[m]
// block tile 64x128, thread micro-tile 8x4, K tiled by 32.
static constexpr int ASTR = 68;   // 64 + 4 pad (keeps 16B alignment)
static constexpr int BSTR = 132;  // 128 + 4 pad

__global__ __launch_bounds__(256) void k_gemm(
    const float* __restrict__ A, const float* __restrict__ W,
    const float* __restrict__ bias, const float* __restrict__ dinv,
    float* __restrict__ hout, int n) {
  __shared__ float As[32][ASTR];  // [k][m]  (transposed)
  __shared__ float Bs[32][BSTR];  // [k][n]  (W transposed)
  const int tid = threadIdx.x;
  const int tm = tid >> 5;  // 0..7  -> rows  tm*8 .. tm*8+7
  const int tn = tid & 31;  // 0..31 -> cols  tn*4 .. tn*4+3
  const int m0 = blockIdx.x * 64;

  float acc[8][4];
#pragma unroll
  for (int i = 0; i < 8; ++i)
#pragma unroll
    for (int j = 0; j < 4; ++j) acc[i][j] = 0.f;

  for (int kt = 0; kt < F; kt += 32) {
    __syncthreads();
#pragma unroll
    for (int l = 0; l < 2; ++l) {
      const int idx = tid + l * 256;
      const int r = idx >> 3;
      const int j = idx & 7;
      const int grow = m0 + r;
      float4 v = make_float4(0.f, 0.f, 0.f, 0.f);
      if (grow < n) v = *(const float4*)(A + (size_t)grow * F + kt + j * 4);
      As[j * 4 + 0][r] = v.x;
      As[j * 4 + 1][r] = v.y;
      As[j * 4 + 2][r] = v.z;
      As[j * 4 + 3][r] = v.w;
    }
#pragma unroll
    for (int l = 0; l < 4; ++l) {
      const int idx = tid + l * 256;
      const int r = idx >> 3;
      const int j = idx & 7;
      const float4 v = *(const float4*)(W + (size_t)r * F + kt + j * 4);
      Bs[j * 4 + 0][r] = v.x;
      Bs[j * 4 + 1][r] = v.y;
      Bs[j * 4 + 2][r] = v.z;
      Bs[j * 4 + 3][r] = v.w;
    }
    __syncthreads();
#pragma unroll
    for (int k = 0; k < 32; ++k) {
      const float4 a0 = *(const float4*)&As[k][tm * 8];
      const float4 a1 = *(const float4*)&As[k][tm * 8 + 4];
      const float4 b = *(const float4*)&Bs[k][tn * 4];
      acc[0][0] += a0.x * b.x; acc[0][1] += a0.x * b.y; acc[0][2] += a0.x * b.z; acc[0][3] += a0.x * b.w;
      acc[1][0] += a0.y * b.x; acc[1][1] += a0.y * b.y; acc[1][2] += a0.y * b.z; acc[1][3] += a0.y * b.w;
      acc[2][0] += a0.z * b.x; acc[2][1] += a0.z * b.y; acc[2][2] += a0.z * b.z; acc[2][3] += a0.z * b.w;
      acc[3][0] += a0.w * b.x; acc[3][1] += a0.w * b.y; acc[3][2] += a0.w * b.z; acc[3][3] += a0.w * b.w;
      acc[4][0] += a1.x * b.x; acc[4][1] += a1.x * b.y; acc[4][2] += a1.x * b.z; acc[4][3] += a1.x * b.w;
      acc[5][0] += a1.y * b.x; acc[5][1] += a1.y * b.y; acc[5][2] += a1.y * b.z; acc[5][3] += a1.y * b.w;
      acc[6][0] += a1.z * b.x; acc[6][1] += a1.z * b.y; acc[6][2] += a1.z * b.z; acc[6][3] += a1.z * b.w;
      acc[7][0] += a1.w * b.x; acc[7][1] += a1.w * b.y; acc[7][2] += a1.w * b.z; acc[7][3] += a1.w * b.w;
    }
  }

  const float4 bv = *(const float4*)(bias + tn * 4);
#pragma unroll
  for (int i = 0; i < 8; ++i) {
    const int grow = m0 + tm * 8 + i;
    if (grow < n) {
      const float dv = dinv[grow];
      float4 o;
      o.x = (acc[i][0] + bv.x) * dv;
      o.y = (acc[i][1] + bv.y) * dv;
      o.z = (acc[i][2] + bv.z) * dv;
      o.w = (acc[i][3] + bv.w) * dv;
      *(float4*)(hout + (size_t)grow * F + tn * 4) = o;
    }
  }
}

// one 64-lane wave per node; two edges per step via half-wave float4 gathers.
// lanes 0..31 take edges beg,beg+2,...; lanes 32..63 take beg+1,beg+3,...
template <bool RELU>
__global__ __launch_bounds__(256) void k_pull(
    const int* __restrict__ rowptr, const int* __restrict__ csr,
    const float* __restrict__ h, const float* __restrict__ dinv,
    float* __restrict__ out, int n) {
  const int wid = (blockIdx.x * blockDim.x + threadIdx.x) >> 6;
  if (wid >= n) return;
  const int lane = threadIdx.x & 63;
  const int half = lane >> 5;
  const int l32 = lane & 31;
  const float4* __restrict__ hv = (const float4*)h;  // 32 float4 per row
  const int beg = rowptr[wid];
  const int end = rowptr[wid + 1];

  float4 acc = make_float4(0.f, 0.f, 0.f, 0.f);
  if (half == 0) acc = hv[(size_t)wid * 32 + l32];  // self loop on half 0

  int k = beg + half;
  // 4-deep unroll: 8 row-gathers in flight per wave
  for (; k + 6 < end; k += 8) {
    const int s0 = csr[k];
    const int s1 = csr[k + 2];
    const int s2 = csr[k + 4];
    const int s3 = csr[k + 6];
    const float4 v0 = hv[(size_t)s0 * 32 + l32];
    const float4 v1 = hv[(size_t)s1 * 32 + l32];
    const float4 v2 = hv[(size_t)s2 * 32 + l32];
    const float4 v3 = hv[(size_t)s3 * 32 + l32];
    acc.x += v0.x + v1.x + v2.x + v3.x;
    acc.y += v0.y + v1.y + v2.y + v3.y;
    acc.z += v0.z + v1.z + v2.z + v3.z;
    acc.w += v0.w + v1.w + v2.w + v3.w;
  }
  for (; k < end; k += 2) {
    const int s = csr[k];
    const float4 v = hv[(size_t)s * 32 + l32];
    acc.x += v.x;
    acc.y += v.y;
    acc.z += v.z;
    acc.w += v.w;
  }

  // combine halves (lane L <-> lane L^32 hold the same 4 columns)
  acc.x += __shfl_xor(acc.x, 32, 64);
  acc.y += __shfl_xor(acc.y, 32, 64);
  acc.z += __shfl_xor(acc.z, 32, 64);
  acc.w += __shfl_xor(acc.w, 32, 64);

  if (half == 0) {
    const float dv = dinv[wid];
    float4 r;
    r.x = acc.x * dv;
    r.y = acc.y * dv;
    r.z = acc.z * dv;
    r.w = acc.w * dv;
    if (RELU) {
      r.x = fmaxf(r.x, 0.f);
      r.y = fmaxf(r.y, 0.f);
      r.z = fmaxf(r.z, 0.f);
      r.w = fmaxf(r.w, 0.f);
    }
    ((float4*)out)[(size_t)wid * 32 + l32] = r;
  }
}

extern "C" void kernel_launch(void* const* d_in, const int* in_sizes, int n_in,
                              void* d_out, int out_size, void* d_ws, size_t ws_size,
                              hipStream_t stream) {
  const float* x  = (const float*)d_in[0];
  const int*   ei = (const int*)d_in[1];
  const float* W1 = (const float*)d_in[2];
  const float* b1 = (const float*)d_in[3];
  const float* W2 = (const float*)d_in[4];
  const float* b2 = (const float*)d_in[5];

  const int N = in_sizes[0] / F;  // 50000
  const int E = in_sizes[1] / 2;  // 1600000
  const int* src = ei;
  const int* dst = ei + E;
  const int R = (N + NR - 1) / NR;  // 391
  const int C = (E + CH - 1) / CH;  // 391

  char* ws = (char*)d_ws;
  int*      rtot    = (int*)(ws);
  int*      rbase   = (int*)(ws + (4u << 10));
  int*      gcur    = (int*)(ws + (8u << 10));
  float*    dinv    = (float*)(ws + (16u << 10));
  int*      rowptr  = (int*)(ws + (256u << 10));
  unsigned* rsorted = (unsigned*)(ws + (1u << 20));
  int*      csr     = (int*)(ws + (8u << 20));
  float*    hbuf    = (float*)(ws + (16u << 20));
  float*    out     = (float*)d_out;  // also layer-1 aggregation buffer

  const int B = 256;
  const int gemmBlocks = (N + 63) / 64;         // 782
  const int pullBlocks = (N * 64 + B - 1) / B;  // 12500

  // CSR build (counting sort, LDS atomics only)
  k_zero_i32<<<1, 512, 0, stream>>>(rtot, R);
  k_hist<<<C, B, 0, stream>>>(dst, E, R, rtot);
  k_scanR<<<1, 512, 0, stream>>>(rtot, R, E, rbase, gcur);
  k_part<<<C, B, 0, stream>>>(src, dst, E, R, gcur, rsorted);
  k_fillR<<<R, B, 0, stream>>>(rsorted, rbase, N, E, rowptr, dinv, csr);

  // layer 1
  k_gemm<<<gemmBlocks, B, 0, stream>>>(x, W1, b1, dinv, hbuf, N);
  k_pull<true><<<pullBlocks, B, 0, stream>>>(rowptr, csr, hbuf, dinv, out, N);

  // layer 2
  k_gemm<<<gemmBlocks, B, 0, stream>>>(out, W2, b2, dinv, hbuf, N);
  k_pull<false><<<pullBlocks, B, 0, stream>>>(rowptr, csr, hbuf, dinv, out, N);
}

// Round 6
// 231.107 us; speedup vs baseline: 26.7627x; 1.4231x over previous
//
#include <hip/hip_runtime.h>

// GCN 2-layer forward, N=50000, F=128, E=1.6M (+ self loops).
//
//   h'   = (x @ W^T + b) * dinv[row]        (stored bf16 -> halves gather bytes)
//   out  = dinv[row] * (h'[row] + sum_{e: dst=row} h'[src[e]])   (+ relu L1)
//
// CSR built via two-level counting sort (LDS atomics only, coalesced writes).
// Pull-mode aggregation: wave per node, two edges per step via half-wave
// uint2 (4xbf16) gathers, f32 accumulation, shfl_xor(32) combine.
// GEMM: register-tiled VALU SGEMM (no f32 MFMA on CDNA4), bf16 pack epilogue.
//
// ws layout:
//   [0]     rtot    R i32
//   [4K]    rbase   R+1 i32
//   [8K]    gcur    R i32
//   [16K]   dinv    N f32    (200 KB)
//   [256K]  rowptr  N+1 i32
//   [1M]    rsorted E u32    (6.4 MB)
//   [8M]    csr     E i32    (6.4 MB)
//   [16M]   hbuf    N*F bf16 (12.8 MB)
// d_out doubles as the layer-1 aggregation output (fully overwritten later).

static constexpr int F = 128;
static constexpr int NR = 128;   // nodes per range (dst>>7)
static constexpr int CH = 4096;  // edges per chunk
static constexpr int RMAX = 512; // max ranges supported (N < 65536)

__device__ __forceinline__ unsigned f2b(float x) {  // f32 -> bf16 bits, RNE
  unsigned u = __float_as_uint(x);
  return (u + 0x7fffu + ((u >> 16) & 1u)) >> 16;
}
__device__ __forceinline__ float b_lo(unsigned u) {
  return __uint_as_float(u << 16);
}
__device__ __forceinline__ float b_hi(unsigned u) {
  return __uint_as_float(u & 0xffff0000u);
}

__global__ void k_zero_i32(int* __restrict__ p, int n) {
  int i = blockIdx.x * blockDim.x + threadIdx.x;
  if (i < n) p[i] = 0;
}

__global__ __launch_bounds__(256) void k_hist(const int* __restrict__ dst,
                                              int E, int R,
                                              int* __restrict__ rtot) {
  __shared__ int h[RMAX];
  for (int i = threadIdx.x; i < R; i += 256) h[i] = 0;
  __syncthreads();
  const int e0 = blockIdx.x * CH;
  const int e1 = min(e0 + CH, E);
  for (int i = e0 + threadIdx.x; i < e1; i += 256)
    atomicAdd(&h[dst[i] >> 7], 1);
  __syncthreads();
  for (int i = threadIdx.x; i < R; i += 256)
    if (h[i]) atomicAdd(&rtot[i], h[i]);
}

__global__ __launch_bounds__(512) void k_scanR(const int* __restrict__ rtot,
                                               int R, int E,
                                               int* __restrict__ rbase,
                                               int* __restrict__ gcur) {
  __shared__ int s[512];
  const int t = threadIdx.x;
  const int v = (t < R) ? rtot[t] : 0;
  s[t] = v;
  __syncthreads();
#pragma unroll
  for (int off = 1; off < 512; off <<= 1) {
    int a = (t >= off) ? s[t - off] : 0;
    __syncthreads();
    s[t] += a;
    __syncthreads();
  }
  if (t < R) {
    const int b = s[t] - v;  // exclusive
    rbase[t] = b;
    gcur[t] = b;
  }
  if (t == 0) rbase[R] = E;
}

__global__ __launch_bounds__(256) void k_part(const int* __restrict__ src,
                                              const int* __restrict__ dst,
                                              int E, int R,
                                              int* __restrict__ gcur,
                                              unsigned* __restrict__ rsorted) {
  __shared__ int h[RMAX];
  __shared__ int cur[RMAX];
  for (int i = threadIdx.x; i < R; i += 256) h[i] = 0;
  __syncthreads();
  const int e0 = blockIdx.x * CH;
  const int e1 = min(e0 + CH, E);
  for (int i = e0 + threadIdx.x; i < e1; i += 256)
    atomicAdd(&h[dst[i] >> 7], 1);
  __syncthreads();
  for (int i = threadIdx.x; i < R; i += 256)
    cur[i] = h[i] ? atomicAdd(&gcur[i], h[i]) : 0;
  __syncthreads();
  for (int i = e0 + threadIdx.x; i < e1; i += 256) {
    const int d = dst[i];
    const int s = src[i];
    const int pos = atomicAdd(&cur[d >> 7], 1);
    rsorted[pos] = ((unsigned)(d & (NR - 1)) << 16) | (unsigned)s;
  }
}

__global__ __launch_bounds__(256) void k_fillR(
    const unsigned* __restrict__ rsorted, const int* __restrict__ rbase,
    int N, int E, int* __restrict__ rowptr, float* __restrict__ dinv,
    int* __restrict__ csr) {
  __shared__ int cnt[NR];
  __shared__ int sc[NR];
  __shared__ int cur[NR];
  const int r = blockIdx.x;
  const int tid = threadIdx.x;
  const int b = rbase[r];
  const int e = rbase[r + 1];
  if (tid < NR) cnt[tid] = 0;
  __syncthreads();
  for (int i = b + tid; i < e; i += 256)
    atomicAdd(&cnt[rsorted[i] >> 16], 1);
  __syncthreads();
  if (tid < NR) sc[tid] = cnt[tid];
  __syncthreads();
#pragma unroll
  for (int off = 1; off < NR; off <<= 1) {
    int a = (tid < NR && tid >= off) ? sc[tid - off] : 0;
    __syncthreads();
    if (tid < NR) sc[tid] += a;
    __syncthreads();
  }
  if (tid < NR) {
    const int excl = sc[tid] - cnt[tid];
    cur[tid] = excl;
    const int node = r * NR + tid;
    if (node < N) {
      rowptr[node] = b + excl;
      dinv[node] = rsqrtf((float)(cnt[tid] + 1));  // +1 self loop
    }
  }
  if (r == 0 && tid == 0) rowptr[N] = E;
  __syncthreads();
  for (int i = b + tid; i < e; i += 256) {
    const unsigned v = rsorted[i];
    const int pos = b + atomicAdd(&cur[v >> 16], 1);
    csr[pos] = (int)(v & 0xFFFFu);
  }
}

// hout[m,:] = bf16( (A[m,:] @ W^T + bias) * dinv[m] )
// block tile 64x128, thread micro-tile 8x4, K tiled by 32.
static constexpr int ASTR = 68;   // 64 + 4 pad (keeps 16B alignment)
static constexpr int BSTR = 132;  // 128 + 4 pad

__global__ __launch_bounds__(256) void k_gemm(
    const float* __restrict__ A, const float* __restrict__ W,
    const float* __restrict__ bias, const float* __restrict__ dinv,
    uint2* __restrict__ hout, int n) {
  __shared__ float As[32][ASTR];  // [k][m]  (transposed)
  __shared__ float Bs[32][BSTR];  // [k][n]  (W transposed)
  const int tid = threadIdx.x;
  const int tm = tid >> 5;  // 0..7  -> rows  tm*8 .. tm*8+7
  const int tn = tid & 31;  // 0..31 -> cols  tn*4 .. tn*4+3
  const int m0 = blockIdx.x * 64;

  float acc[8][4];
#pragma unroll
  for (int i = 0; i < 8; ++i)
#pragma unroll
    for (int j = 0; j < 4; ++j) acc[i][j] = 0.f;

  for (int kt = 0; kt < F; kt += 32) {
    __syncthreads();
#pragma unroll
    for (int l = 0; l < 2; ++l) {
      const int idx = tid + l * 256;
      const int r = idx >> 3;
      const int j = idx & 7;
      const int grow = m0 + r;
      float4 v = make_float4(0.f, 0.f, 0.f, 0.f);
      if (grow < n) v = *(const float4*)(A + (size_t)grow * F + kt + j * 4);
      As[j * 4 + 0][r] = v.x;
      As[j * 4 + 1][r] = v.y;
      As[j * 4 + 2][r] = v.z;
      As[j * 4 + 3][r] = v.w;
    }
#pragma unroll
    for (int l = 0; l < 4; ++l) {
      const int idx = tid + l * 256;
      const int r = idx >> 3;
      const int j = idx & 7;
      const float4 v = *(const float4*)(W + (size_t)r * F + kt + j * 4);
      Bs[j * 4 + 0][r] = v.x;
      Bs[j * 4 + 1][r] = v.y;
      Bs[j * 4 + 2][r] = v.z;
      Bs[j * 4 + 3][r] = v.w;
    }
    __syncthreads();
#pragma unroll
    for (int k = 0; k < 32; ++k) {
      const float4 a0 = *(const float4*)&As[k][tm * 8];
      const float4 a1 = *(const float4*)&As[k][tm * 8 + 4];
      const float4 b = *(const float4*)&Bs[k][tn * 4];
      acc[0][0] += a0.x * b.x; acc[0][1] += a0.x * b.y; acc[0][2] += a0.x * b.z; acc[0][3] += a0.x * b.w;
      acc[1][0] += a0.y * b.x; acc[1][1] += a0.y * b.y; acc[1][2] += a0.y * b.z; acc[1][3] += a0.y * b.w;
      acc[2][0] += a0.z * b.x; acc[2][1] += a0.z * b.y; acc[2][2] += a0.z * b.z; acc[2][3] += a0.z * b.w;
      acc[3][0] += a0.w * b.x; acc[3][1] += a0.w * b.y; acc[3][2] += a0.w * b.z; acc[3][3] += a0.w * b.w;
      acc[4][0] += a1.x * b.x; acc[4][1] += a1.x * b.y; acc[4][2] += a1.x * b.z; acc[4][3] += a1.x * b.w;
      acc[5][0] += a1.y * b.x; acc[5][1] += a1.y * b.y; acc[5][2] += a1.y * b.z; acc[5][3] += a1.y * b.w;
      acc[6][0] += a1.z * b.x; acc[6][1] += a1.z * b.y; acc[6][2] += a1.z * b.z; acc[6][3] += a1.z * b.w;
      acc[7][0] += a1.w * b.x; acc[7][1] += a1.w * b.y; acc[7][2] += a1.w * b.z; acc[7][3] += a1.w * b.w;
    }
  }

  const float4 bv = *(const float4*)(bias + tn * 4);
#pragma unroll
  for (int i = 0; i < 8; ++i) {
    const int grow = m0 + tm * 8 + i;
    if (grow < n) {
      const float dv = dinv[grow];
      const float ox = (acc[i][0] + bv.x) * dv;
      const float oy = (acc[i][1] + bv.y) * dv;
      const float oz = (acc[i][2] + bv.z) * dv;
      const float ow = (acc[i][3] + bv.w) * dv;
      uint2 p;
      p.x = f2b(ox) | (f2b(oy) << 16);
      p.y = f2b(oz) | (f2b(ow) << 16);
      hout[(size_t)grow * 32 + tn] = p;  // 32 uint2 (=128 bf16) per row
    }
  }
}

// one 64-lane wave per node; two edges per step via half-wave uint2 gathers
// (4 bf16 per lane). lanes 0..31: edges beg,beg+2,...; lanes 32..63: beg+1,...
template <bool RELU>
__global__ __launch_bounds__(256) void k_pull(
    const int* __restrict__ rowptr, const int* __restrict__ csr,
    const uint2* __restrict__ h, const float* __restrict__ dinv,
    float* __restrict__ out, int n) {
  const int wid = (blockIdx.x * blockDim.x + threadIdx.x) >> 6;
  if (wid >= n) return;
  const int lane = threadIdx.x & 63;
  const int half = lane >> 5;
  const int l32 = lane & 31;
  const int beg = rowptr[wid];
  const int end = rowptr[wid + 1];

  float4 acc = make_float4(0.f, 0.f, 0.f, 0.f);
  if (half == 0) {  // self loop on half 0
    const uint2 u = h[(size_t)wid * 32 + l32];
    acc.x = b_lo(u.x); acc.y = b_hi(u.x);
    acc.z = b_lo(u.y); acc.w = b_hi(u.y);
  }

  int k = beg + half;
  // 4-deep unroll: 8 row-gathers in flight per wave
  for (; k + 6 < end; k += 8) {
    const int s0 = csr[k];
    const int s1 = csr[k + 2];
    const int s2 = csr[k + 4];
    const int s3 = csr[k + 6];
    const uint2 u0 = h[(size_t)s0 * 32 + l32];
    const uint2 u1 = h[(size_t)s1 * 32 + l32];
    const uint2 u2 = h[(size_t)s2 * 32 + l32];
    const uint2 u3 = h[(size_t)s3 * 32 + l32];
    acc.x += b_lo(u0.x) + b_lo(u1.x) + b_lo(u2.x) + b_lo(u3.x);
    acc.y += b_hi(u0.x) + b_hi(u1.x) + b_hi(u2.x) + b_hi(u3.x);
    acc.z += b_lo(u0.y) + b_lo(u1.y) + b_lo(u2.y) + b_lo(u3.y);
    acc.w += b_hi(u0.y) + b_hi(u1.y) + b_hi(u2.y) + b_hi(u3.y);
  }
  for (; k < end; k += 2) {
    const uint2 u = h[(size_t)csr[k] * 32 + l32];
    acc.x += b_lo(u.x);
    acc.y += b_hi(u.x);
    acc.z += b_lo(u.y);
    acc.w += b_hi(u.y);
  }

  // combine halves (lane L <-> lane L^32 hold the same 4 columns)
  acc.x += __shfl_xor(acc.x, 32, 64);
  acc.y += __shfl_xor(acc.y, 32, 64);
  acc.z += __shfl_xor(acc.z, 32, 64);
  acc.w += __shfl_xor(acc.w, 32, 64);

  if (half == 0) {
    const float dv = dinv[wid];
    float4 r;
    r.x = acc.x * dv;
    r.y = acc.y * dv;
    r.z = acc.z * dv;
    r.w = acc.w * dv;
    if (RELU) {
      r.x = fmaxf(r.x, 0.f);
      r.y = fmaxf(r.y, 0.f);
      r.z = fmaxf(r.z, 0.f);
      r.w = fmaxf(r.w, 0.f);
    }
    ((float4*)out)[(size_t)wid * 32 + l32] = r;
  }
}

extern "C" void kernel_launch(void* const* d_in, const int* in_sizes, int n_in,
                              void* d_out, int out_size, void* d_ws, size_t ws_size,
                              hipStream_t stream) {
  const float* x  = (const float*)d_in[0];
  const int*   ei = (const int*)d_in[1];
  const float* W1 = (const float*)d_in[2];
  const float* b1 = (const float*)d_in[3];
  const float* W2 = (const float*)d_in[4];
  const float* b2 = (const float*)d_in[5];

  const int N = in_sizes[0] / F;  // 50000
  const int E = in_sizes[1] / 2;  // 1600000
  const int* src = ei;
  const int* dst = ei + E;
  const int R = (N + NR - 1) / NR;  // 391
  const int C = (E + CH - 1) / CH;  // 391

  char* ws = (char*)d_ws;
  int*      rtot    = (int*)(ws);
  int*      rbase   = (int*)(ws + (4u << 10));
  int*      gcur    = (int*)(ws + (8u << 10));
  float*    dinv    = (float*)(ws + (16u << 10));
  int*      rowptr  = (int*)(ws + (256u << 10));
  unsigned* rsorted = (unsigned*)(ws + (1u << 20));
  int*      csr     = (int*)(ws + (8u << 20));
  uint2*    hbuf    = (uint2*)(ws + (16u << 20));  // N*F bf16
  float*    out     = (float*)d_out;  // also layer-1 aggregation buffer

  const int B = 256;
  const int gemmBlocks = (N + 63) / 64;         // 782
  const int pullBlocks = (N * 64 + B - 1) / B;  // 12500

  // CSR build (counting sort, LDS atomics only)
  k_zero_i32<<<1, 512, 0, stream>>>(rtot, R);
  k_hist<<<C, B, 0, stream>>>(dst, E, R, rtot);
  k_scanR<<<1, 512, 0, stream>>>(rtot, R, E, rbase, gcur);
  k_part<<<C, B, 0, stream>>>(src, dst, E, R, gcur, rsorted);
  k_fillR<<<R, B, 0, stream>>>(rsorted, rbase, N, E, rowptr, dinv, csr);

  // layer 1
  k_gemm<<<gemmBlocks, B, 0, stream>>>(x, W1, b1, dinv, hbuf, N);
  k_pull<true><<<pullBlocks, B, 0, stream>>>(rowptr, csr, hbuf, dinv, out, N);

  // layer 2
  k_gemm<<<gemmBlocks, B, 0, stream>>>(out, W2, b2, dinv, hbuf, N);
  k_pull<false><<<pullBlocks, B, 0, stream>>>(rowptr, csr, hbuf, dinv, out, N);
}